// Round 6
// baseline (258.430 us; speedup 1.0000x reference)
//
#include <hip/hip_runtime.h>

// out[b,c,i,j] = x[b, c, 2*i + (idx[b,i,j]>>1), 2*j + (idx[b,i,j]&1)]
// x: (16,64,512,512) f32, idx: (16,256,256) i32, out: (16,64,256,256) f32

#define NB 16
#define NC 64
#define NH 512
#define NW 512
#define HO 256
#define WO 256
#define CG 4                 // channel groups (threads per (b,i) row point)
#define CPT (NC / CG)        // channels per thread = 16

typedef float f32x4 __attribute__((ext_vector_type(4)));
typedef float f32x2 __attribute__((ext_vector_type(2)));
typedef int   i32x2 __attribute__((ext_vector_type(2)));

// (256,8): pin 8 waves/SIMD (32/CU) -> VGPR <= 64, full occupancy guaranteed.
__global__ __launch_bounds__(256, 8) void pool_gather_kernel(
    const float* __restrict__ x,
    const int*   __restrict__ idx,
    float*       __restrict__ out)
{
    // Lane l of a wave owns half-windows {l, l+64} of output row i:
    // out cols {2l, 2l+1} and {128+2l, 129+2l}. All vmem instructions are
    // dense contiguous bursts across the wave.
    int t  = blockIdx.x * 256 + threadIdx.x;
    int l  = t & 63;                 // lane within wave
    int i  = (t >> 6) & (HO - 1);    // 0..255
    int b  = (t >> 14) & (NB - 1);   // 0..15
    int cg = t >> 18;                // 0..3
    int c0 = cg * CPT;

    // idx for this thread's 4 output columns, reused across 16 channels.
    const int* ib = idx + ((size_t)b * HO + (size_t)i) * WO;
    const i32x2 eL = *reinterpret_cast<const i32x2*>(ib + 2 * l);        // cols 2l,2l+1
    const i32x2 eH = *reinterpret_cast<const i32x2*>(ib + 128 + 2 * l);  // cols 128+2l,129+2l

    // Running pointers (strength-reduced): one 64-bit add per iter each.
    const float* p = x + ((size_t)(b * NC + c0) * NH + (size_t)(2 * i)) * NW + 4 * l;
    float* q = out + ((size_t)(b * NC + c0) * HO + (size_t)i) * WO + 2 * l;

    #pragma unroll 4
    for (int c = 0; c < CPT; ++c) {
        // x row 2i: [0,1KB)+[1KB,2KB); row 2i+1: [2KB,3KB)+[3KB,4KB)
        f32x4 a  = __builtin_nontemporal_load(reinterpret_cast<const f32x4*>(p));
        f32x4 ah = __builtin_nontemporal_load(reinterpret_cast<const f32x4*>(p + NW / 2));
        f32x4 bq = __builtin_nontemporal_load(reinterpret_cast<const f32x4*>(p + NW));
        f32x4 bh = __builtin_nontemporal_load(reinterpret_cast<const f32x4*>(p + NW + NW / 2));

        f32x2 oL, oH;
        {   int e = eL.x;  // out col 2l: candidates a.x/a.y/bq.x/bq.y
            oL.x = (e & 1) ? ((e & 2) ? bq.y : a.y) : ((e & 2) ? bq.x : a.x); }
        {   int e = eL.y;  // out col 2l+1: a.z/a.w/bq.z/bq.w
            oL.y = (e & 1) ? ((e & 2) ? bq.w : a.w) : ((e & 2) ? bq.z : a.z); }
        {   int e = eH.x;  // out col 128+2l
            oH.x = (e & 1) ? ((e & 2) ? bh.y : ah.y) : ((e & 2) ? bh.x : ah.x); }
        {   int e = eH.y;  // out col 129+2l
            oH.y = (e & 1) ? ((e & 2) ? bh.w : ah.w) : ((e & 2) ? bh.z : ah.z); }

        // single change vs round 4: stream the write-once output past L3
        __builtin_nontemporal_store(oL, reinterpret_cast<f32x2*>(q));
        __builtin_nontemporal_store(oH, reinterpret_cast<f32x2*>(q + 128));

        p += (size_t)NH * NW;   // next channel plane
        q += HO * WO;
    }
}

extern "C" void kernel_launch(void* const* d_in, const int* in_sizes, int n_in,
                              void* d_out, int out_size, void* d_ws, size_t ws_size,
                              hipStream_t stream)
{
    const float* x   = (const float*)d_in[0];
    const int*   idx = (const int*)d_in[1];
    float*       out = (float*)d_out;

    const int total_threads = NB * HO * 64 * CG;  // 1,048,576
    pool_gather_kernel<<<total_threads / 256, 256, 0, stream>>>(x, idx, out);
}

// Round 7
// 235.619 us; speedup vs baseline: 1.0968x; 1.0968x over previous
//
#include <hip/hip_runtime.h>

// out[b,c,i,j] = x[b, c, 2*i + (idx[b,i,j]>>1), 2*j + (idx[b,i,j]&1)]
// x: (16,64,512,512) f32, idx: (16,256,256) i32, out: (16,64,256,256) f32
//
// Config notes (A/B history):
//  - nt LOADS + plain STORES is optimal: nt stores cost −9% (258 vs 237 µs);
//    plain stores let L2 write-combine the 8B/lane stores into full lines.
//  - __launch_bounds__(256,8) pins VGPR<=64 -> 32 waves/CU.
//  - All vmem instructions are dense contiguous wave-bursts (1KB loads).

#define NB 16
#define NC 64
#define NH 512
#define NW 512
#define HO 256
#define WO 256
#define CG 4                 // channel groups (threads per (b,i) row point)
#define CPT (NC / CG)        // channels per thread = 16

typedef float f32x4 __attribute__((ext_vector_type(4)));
typedef float f32x2 __attribute__((ext_vector_type(2)));
typedef int   i32x2 __attribute__((ext_vector_type(2)));

__global__ __launch_bounds__(256, 8) void pool_gather_kernel(
    const float* __restrict__ x,
    const int*   __restrict__ idx,
    float*       __restrict__ out)
{
    // Lane l of a wave owns half-windows {l, l+64} of output row i:
    // out cols {2l, 2l+1} and {128+2l, 129+2l}.
    int t  = blockIdx.x * 256 + threadIdx.x;
    int l  = t & 63;                 // lane within wave
    int i  = (t >> 6) & (HO - 1);    // 0..255
    int b  = (t >> 14) & (NB - 1);   // 0..15
    int cg = t >> 18;                // 0..3
    int c0 = cg * CPT;

    // idx for this thread's 4 output columns, reused across 16 channels.
    const int* ib = idx + ((size_t)b * HO + (size_t)i) * WO;
    const i32x2 eL = *reinterpret_cast<const i32x2*>(ib + 2 * l);        // cols 2l,2l+1
    const i32x2 eH = *reinterpret_cast<const i32x2*>(ib + 128 + 2 * l);  // cols 128+2l,129+2l

    // Running pointers (strength-reduced): one 64-bit add per iter each.
    const float* p = x + ((size_t)(b * NC + c0) * NH + (size_t)(2 * i)) * NW + 4 * l;
    float* q = out + ((size_t)(b * NC + c0) * HO + (size_t)i) * WO + 2 * l;

    #pragma unroll 4
    for (int c = 0; c < CPT; ++c) {
        // x row 2i: [0,1KB)+[1KB,2KB); row 2i+1: [2KB,3KB)+[3KB,4KB)
        f32x4 a  = __builtin_nontemporal_load(reinterpret_cast<const f32x4*>(p));
        f32x4 ah = __builtin_nontemporal_load(reinterpret_cast<const f32x4*>(p + NW / 2));
        f32x4 bq = __builtin_nontemporal_load(reinterpret_cast<const f32x4*>(p + NW));
        f32x4 bh = __builtin_nontemporal_load(reinterpret_cast<const f32x4*>(p + NW + NW / 2));

        f32x2 oL, oH;
        {   int e = eL.x;  // out col 2l: candidates a.x/a.y/bq.x/bq.y
            oL.x = (e & 1) ? ((e & 2) ? bq.y : a.y) : ((e & 2) ? bq.x : a.x); }
        {   int e = eL.y;  // out col 2l+1: a.z/a.w/bq.z/bq.w
            oL.y = (e & 1) ? ((e & 2) ? bq.w : a.w) : ((e & 2) ? bq.z : a.z); }
        {   int e = eH.x;  // out col 128+2l
            oH.x = (e & 1) ? ((e & 2) ? bh.y : ah.y) : ((e & 2) ? bh.x : ah.x); }
        {   int e = eH.y;  // out col 129+2l
            oH.y = (e & 1) ? ((e & 2) ? bh.w : ah.w) : ((e & 2) ? bh.z : ah.z); }

        // plain (cached) stores — measured best
        *reinterpret_cast<f32x2*>(q)       = oL;
        *reinterpret_cast<f32x2*>(q + 128) = oH;

        p += (size_t)NH * NW;   // next channel plane
        q += HO * WO;
    }
}

extern "C" void kernel_launch(void* const* d_in, const int* in_sizes, int n_in,
                              void* d_out, int out_size, void* d_ws, size_t ws_size,
                              hipStream_t stream)
{
    const float* x   = (const float*)d_in[0];
    const int*   idx = (const int*)d_in[1];
    float*       out = (float*)d_out;

    const int total_threads = NB * HO * 64 * CG;  // 1,048,576
    pool_gather_kernel<<<total_threads / 256, 256, 0, stream>>>(x, idx, out);
}